// Round 1
// baseline (1864.665 us; speedup 1.0000x reference)
//
#include <hip/hip_runtime.h>
#include <math.h>

#define B_   16
#define S_   1056
#define DM_  256
#define H_   8
#define DK_  32
#define TXT_ 32
#define VID_ 1024
#define SS_  (S_*S_)          // 1115136
#define NQT_ (S_/8)           // 132 q-tiles of 8 rows

#define LOG2_10000f 13.28771237954945f
#define LOG2_GAMMAf (-0.15200309344504995f)   // log2(0.9)
#define RSQRT_DKf   0.17677669529663687f      // 1/sqrt(32)
#define TWO_PIf     6.283185307179586f

// ---------------- mask + loss partials ----------------
__global__ __launch_bounds__(256) void k_mask(const float* __restrict__ lvr,
                       const int* __restrict__ row_idx, const int* __restrict__ col_idx,
                       float* __restrict__ mask, float* __restrict__ partials)
{
    int idx = blockIdx.x*256 + threadIdx.x;           // exactly SS_ threads
    unsigned ui = (unsigned)idx;
    int i = ui / S_;
    int j = (int)(ui - (unsigned)i*S_);
    float vr, lm;
    if (i == j) { vr = 0.f; lm = 1.f; }
    else {
        float t = lvr[(size_t)row_idx[idx]*VID_ + col_idx[idx]];
        float sg = 1.f/(1.f + expf(-t));
        vr = sg; lm = sg;
    }
    float dmat = (i >= j) ? exp2f((float)(i-j)*LOG2_GAMMAf) : 0.f;
    mask[idx] = dmat * lm;
    // block reduce |video_ret| (sigmoid > 0, so abs == value)
    float s = vr;
    #pragma unroll
    for (int m=1; m<64; m<<=1) s += __shfl_xor(s, m, 64);
    __shared__ float ws4[4];
    if ((threadIdx.x & 63) == 0) ws4[threadIdx.x>>6] = s;
    __syncthreads();
    if (threadIdx.x == 0) partials[blockIdx.x] = ws4[0]+ws4[1]+ws4[2]+ws4[3];
}

__global__ __launch_bounds__(256) void k_loss(const float* __restrict__ partials,
                                              float* __restrict__ out_loss)
{
    float s = 0.f;
    for (int i = threadIdx.x; i < SS_/256; i += 256) s += partials[i];
    #pragma unroll
    for (int m=1; m<64; m<<=1) s += __shfl_xor(s, m, 64);
    __shared__ float ws4[4];
    if ((threadIdx.x & 63) == 0) ws4[threadIdx.x>>6] = s;
    __syncthreads();
    if (threadIdx.x == 0) out_loss[0] = (ws4[0]+ws4[1]+ws4[2]+ws4[3]) * (1.f/(float)SS_);
}

// ---------------- W_out transpose ----------------
__global__ __launch_bounds__(256) void k_wot(const float* __restrict__ Wout,
                                             float* __restrict__ WoT)
{
    int t = blockIdx.x*256 + threadIdx.x;     // 65536 elems
    WoT[t] = Wout[(t & 255)*DM_ + (t >> 8)];
}

// ---------------- QKV projection (16 rows/block, 256 threads) ----------------
// xt layout: [matrix][dim e][row rr] with pad-20 rows (16B-aligned for b128 reads)
__global__ __launch_bounds__(256) void k_qkv(const float* __restrict__ src,
    const float* __restrict__ Wq, const float* __restrict__ Wk, const float* __restrict__ Wv,
    float* __restrict__ Qh, float* __restrict__ Kh, float* __restrict__ Vh, int is_txt)
{
    __shared__ float xt[3][DM_][20];
    int tid = threadIdx.x;
    int r0 = blockIdx.x * 16;
    int b, srow0;
    if (is_txt) { b = r0 >> 5;  srow0 = r0 & 31; }
    else        { b = r0 >> 10; srow0 = TXT_ + (r0 & 1023); }

    // transform + stage: 2048 pair-tasks (16 rows x 128 pairs)
    for (int it = 0; it < 8; ++it) {
        int task = it*256 + tid;
        int k  = task >> 4;          // 0..127
        int rr = task & 15;
        int srow = srow0 + rr;
        float2 x01 = ((const float2*)(src + ((size_t)b*S_ + srow)*DM_))[k];
        if (is_txt) {
            float xe  = (float)(srow + 1) * (TWO_PIf/(32.f + 1e-6f));
            float arg = xe * exp2f(-((float)k*(1.f/128.f))*LOG2_10000f);
            float p0 = sinf(arg), p1 = cosf(arg);
            xt[0][2*k  ][rr] = x01.x + p0;
            xt[0][2*k+1][rr] = x01.y + p1;
            xt[1][2*k  ][rr] = x01.x + p0;
            xt[1][2*k+1][rr] = x01.y + p1;
        } else {
            int l = srow - TXT_;
            float inv_freq = exp2f(-((float)k*(1.f/128.f))*LOG2_10000f);
            float arg = (float)l * inv_freq;
            float sn = sinf(arg), cs = cosf(arg);
            float base = ((float)(2*k) + 102.4f) * (1.f/358.4f);
            float scale = exp2f(((float)l*(1.f/512.f)) * log2f(base));
            float rsc = 1.f/scale;
            float y0 = x01.x*cs - x01.y*sn;
            float y1 = x01.y*cs + x01.x*sn;
            xt[0][2*k  ][rr] = y0*scale;  xt[0][2*k+1][rr] = y1*scale;
            xt[1][2*k  ][rr] = y0*rsc;    xt[1][2*k+1][rr] = y1*rsc;
        }
        xt[2][2*k  ][rr] = x01.x;
        xt[2][2*k+1][rr] = x01.y;
    }
    __syncthreads();

    int og = tid & 63, rg = tid >> 6;   // o = og*4 + c ; rr = rg*4 + jr
    float aq[4][4], ak[4][4], av[4][4];
    #pragma unroll
    for (int c=0;c<4;c++)
      #pragma unroll
      for (int jr=0;jr<4;jr++){ aq[c][jr]=0.f; ak[c][jr]=0.f; av[c][jr]=0.f; }

    for (int e = 0; e < DM_; ++e) {
        float4 xq = *(const float4*)&xt[0][e][rg*4];
        float4 xk = *(const float4*)&xt[1][e][rg*4];
        float4 xv = *(const float4*)&xt[2][e][rg*4];
        float4 wq = *(const float4*)&Wq[e*DM_ + og*4];
        float4 wk = *(const float4*)&Wk[e*DM_ + og*4];
        float4 wv = *(const float4*)&Wv[e*DM_ + og*4];
        float xqa[4] = {xq.x,xq.y,xq.z,xq.w};
        float xka[4] = {xk.x,xk.y,xk.z,xk.w};
        float xva[4] = {xv.x,xv.y,xv.z,xv.w};
        #pragma unroll
        for (int jr=0;jr<4;jr++){
            aq[0][jr] = fmaf(xqa[jr], wq.x, aq[0][jr]);
            aq[1][jr] = fmaf(xqa[jr], wq.y, aq[1][jr]);
            aq[2][jr] = fmaf(xqa[jr], wq.z, aq[2][jr]);
            aq[3][jr] = fmaf(xqa[jr], wq.w, aq[3][jr]);
            ak[0][jr] = fmaf(xka[jr], wk.x, ak[0][jr]);
            ak[1][jr] = fmaf(xka[jr], wk.y, ak[1][jr]);
            ak[2][jr] = fmaf(xka[jr], wk.z, ak[2][jr]);
            ak[3][jr] = fmaf(xka[jr], wk.w, ak[3][jr]);
            av[0][jr] = fmaf(xva[jr], wv.x, av[0][jr]);
            av[1][jr] = fmaf(xva[jr], wv.y, av[1][jr]);
            av[2][jr] = fmaf(xva[jr], wv.z, av[2][jr]);
            av[3][jr] = fmaf(xva[jr], wv.w, av[3][jr]);
        }
    }
    int head = og >> 3;          // (og*4)>>5
    int dbase = (og & 7) * 4;    // (og*4)&31
    #pragma unroll
    for (int jr=0;jr<4;jr++){
        int srow = srow0 + rg*4 + jr;
        size_t off = ((size_t)(b*H_ + head)*S_ + srow)*DK_ + dbase;
        float4 q4 = make_float4(aq[0][jr]*RSQRT_DKf, aq[1][jr]*RSQRT_DKf,
                                aq[2][jr]*RSQRT_DKf, aq[3][jr]*RSQRT_DKf);
        float4 k4 = make_float4(ak[0][jr], ak[1][jr], ak[2][jr], ak[3][jr]);
        float4 v4 = make_float4(av[0][jr], av[1][jr], av[2][jr], av[3][jr]);
        *(float4*)&Qh[off] = q4;
        *(float4*)&Kh[off] = k4;
        *(float4*)&Vh[off] = v4;
    }
}

// ---------------- attention: block = (b, 8-row q-tile), all 8 heads ----------------
__global__ __launch_bounds__(256) void k_attn(const float* __restrict__ Qh,
    const float* __restrict__ Kh, const float* __restrict__ Vh,
    const float* __restrict__ mask, float* __restrict__ ctx, float* __restrict__ att)
{
    __shared__ float e_lds[8][S_];
    __shared__ float denom_l[8];
    int tid = threadIdx.x;
    int blk = blockIdx.x;
    int b  = blk / NQT_;
    int qt = blk - b*NQT_;
    int q0 = qt * 8;

    int kb = tid & 63;      // one wave per qp
    int qp = tid >> 6;      // handles q rows qp and qp+4
    float att0[17], att1[17];
    #pragma unroll
    for (int j=0;j<17;j++){ att0[j]=0.f; att1[j]=0.f; }

    const float* mrow0 = mask + (size_t)(q0+qp)*S_;
    const float* mrow1 = mask + (size_t)(q0+qp+4)*S_;

    for (int h = 0; h < H_; ++h) {
        const float* qp0 = Qh + ((size_t)(b*H_+h)*S_ + q0+qp)*DK_;
        float qr0[DK_], qr1[DK_];
        #pragma unroll
        for (int d4=0; d4<8; ++d4){
            float4 a = *(const float4*)(qp0 + d4*4);
            qr0[d4*4+0]=a.x; qr0[d4*4+1]=a.y; qr0[d4*4+2]=a.z; qr0[d4*4+3]=a.w;
            float4 c = *(const float4*)(qp0 + 4*DK_ + d4*4);
            qr1[d4*4+0]=c.x; qr1[d4*4+1]=c.y; qr1[d4*4+2]=c.z; qr1[d4*4+3]=c.w;
        }
        const float* Kbh = Kh + (size_t)(b*H_+h)*S_*DK_;
        float ps0 = 0.f, ps1 = 0.f;
        #pragma unroll
        for (int kt = 0; kt < 17; ++kt) {
            int k = kt*64 + kb;
            if (k < S_) {
                const float* kr = Kbh + (size_t)k*DK_;
                float d0 = 0.f, d1 = 0.f;
                #pragma unroll
                for (int dq=0; dq<8; ++dq){
                    float4 kv = *(const float4*)(kr + dq*4);
                    d0 = fmaf(qr0[dq*4+0], kv.x, d0);
                    d0 = fmaf(qr0[dq*4+1], kv.y, d0);
                    d0 = fmaf(qr0[dq*4+2], kv.z, d0);
                    d0 = fmaf(qr0[dq*4+3], kv.w, d0);
                    d1 = fmaf(qr1[dq*4+0], kv.x, d1);
                    d1 = fmaf(qr1[dq*4+1], kv.y, d1);
                    d1 = fmaf(qr1[dq*4+2], kv.z, d1);
                    d1 = fmaf(qr1[dq*4+3], kv.w, d1);
                }
                float e0 = expf(d0 * mrow0[k]);   // scores tiny -> safe w/o max-sub
                float e1 = expf(d1 * mrow1[k]);
                e_lds[qp  ][k] = e0;
                e_lds[qp+4][k] = e1;
                ps0 += e0; ps1 += e1;
            }
        }
        #pragma unroll
        for (int m=1; m<64; m<<=1){ ps0 += __shfl_xor(ps0, m, 64); ps1 += __shfl_xor(ps1, m, 64); }
        if (kb == 0){ denom_l[qp] = 1.f/ps0; denom_l[qp+4] = 1.f/ps1; }
        float rd0 = 1.f/ps0, rd1 = 1.f/ps1;
        // att accumulation (own e slots, same-thread RAW in LDS is safe)
        #pragma unroll
        for (int kt=0; kt<17; ++kt){
            int k = kt*64 + kb;
            if (k < S_){
                att0[kt] = fmaf(e_lds[qp  ][k], rd0*0.125f, att0[kt]);
                att1[kt] = fmaf(e_lds[qp+4][k], rd1*0.125f, att1[kt]);
            }
        }
        __syncthreads();   // e_lds + denom visible to all
        // phase 3: ctx = p @ V ; remap threads to (q row, d)
        int dd = tid & 31, qq = tid >> 5;
        const float* Vp = Vh + (size_t)(b*H_+h)*S_*DK_ + dd;
        float acc = 0.f;
        for (int k0 = 0; k0 < S_; k0 += 4){
            float4 e4 = *(const float4*)&e_lds[qq][k0];
            acc = fmaf(e4.x, Vp[(k0+0)*DK_], acc);
            acc = fmaf(e4.y, Vp[(k0+1)*DK_], acc);
            acc = fmaf(e4.z, Vp[(k0+2)*DK_], acc);
            acc = fmaf(e4.w, Vp[(k0+3)*DK_], acc);
        }
        ctx[((size_t)b*S_ + q0+qq)*DM_ + h*DK_ + dd] = acc * denom_l[qq];
        __syncthreads();   // before next head overwrites e_lds
    }
    // write att (block exclusively owns these rows)
    #pragma unroll
    for (int kt=0; kt<17; ++kt){
        int k = kt*64 + kb;
        if (k < S_){
            att[((size_t)b*S_ + q0+qp  )*S_ + k] = att0[kt];
            att[((size_t)b*S_ + q0+qp+4)*S_ + k] = att1[kt];
        }
    }
}

// ---------------- out projection: out = ctx @ WoT + b ----------------
__global__ __launch_bounds__(256) void k_outproj(const float* __restrict__ ctxp,
    const float* __restrict__ WoT, const float* __restrict__ bias, float* __restrict__ out)
{
    __shared__ float ct[DM_][20];
    int tid = threadIdx.x;
    int r0 = blockIdx.x * 16;
    for (int it = 0; it < 16; ++it) {
        int task = it*256 + tid;
        int col = task >> 4;
        int rr  = task & 15;
        ct[col][rr] = ctxp[(size_t)(r0+rr)*DM_ + col];
    }
    __syncthreads();
    int og = tid & 63, rg = tid >> 6;
    float acc[4][4];
    #pragma unroll
    for (int c=0;c<4;c++)
      #pragma unroll
      for (int jr=0;jr<4;jr++) acc[c][jr] = 0.f;
    for (int e = 0; e < DM_; ++e){
        float4 x4 = *(const float4*)&ct[e][rg*4];
        float4 w4 = *(const float4*)&WoT[e*DM_ + og*4];
        float xa[4] = {x4.x,x4.y,x4.z,x4.w};
        #pragma unroll
        for (int jr=0;jr<4;jr++){
            acc[0][jr] = fmaf(xa[jr], w4.x, acc[0][jr]);
            acc[1][jr] = fmaf(xa[jr], w4.y, acc[1][jr]);
            acc[2][jr] = fmaf(xa[jr], w4.z, acc[2][jr]);
            acc[3][jr] = fmaf(xa[jr], w4.w, acc[3][jr]);
        }
    }
    float4 b4 = *(const float4*)&bias[og*4];
    #pragma unroll
    for (int jr=0;jr<4;jr++){
        int r = r0 + rg*4 + jr;
        float4 o4 = make_float4(acc[0][jr]+b4.x, acc[1][jr]+b4.y,
                                acc[2][jr]+b4.z, acc[3][jr]+b4.w);
        *(float4*)&out[(size_t)r*DM_ + og*4] = o4;
    }
}

extern "C" void kernel_launch(void* const* d_in, const int* in_sizes, int n_in,
                              void* d_out, int out_size, void* d_ws, size_t ws_size,
                              hipStream_t stream)
{
    (void)in_sizes; (void)n_in; (void)out_size; (void)ws_size;
    const float* src  = (const float*)d_in[0];
    const float* Wtq  = (const float*)d_in[1];
    const float* Wtk  = (const float*)d_in[2];
    const float* Wtv  = (const float*)d_in[3];
    const float* Wvq  = (const float*)d_in[4];
    const float* Wvk  = (const float*)d_in[5];
    const float* Wvv  = (const float*)d_in[6];
    const float* lvr  = (const float*)d_in[7];
    const float* Wout = (const float*)d_in[8];
    const float* bout = (const float*)d_in[9];
    const int*   rid  = (const int*)d_in[10];
    const int*   cid  = (const int*)d_in[11];

    const size_t QKV_SZ = (size_t)B_*H_*S_*DK_;   // 4,325,376
    float* ws       = (float*)d_ws;
    float* mask     = ws;                          // SS_
    float* Qh       = mask + SS_;
    float* Kh       = Qh + QKV_SZ;
    float* Vh       = Kh + QKV_SZ;
    float* ctx      = Vh + QKV_SZ;                 // B*S*DM
    float* WoT      = ctx + (size_t)B_*S_*DM_;     // 65536
    float* partials = WoT + DM_*DM_;               // 4356

    float* out  = (float*)d_out;
    float* att  = out + (size_t)B_*S_*DM_;
    float* loss = att + (size_t)B_*S_*S_;

    k_mask<<<SS_/256, 256, 0, stream>>>(lvr, rid, cid, mask, partials);
    k_wot<<<DM_*DM_/256, 256, 0, stream>>>(Wout, WoT);
    k_qkv<<<(B_*TXT_)/16, 256, 0, stream>>>(src, Wtq, Wtk, Wtv, Qh, Kh, Vh, 1);
    k_qkv<<<(B_*VID_)/16, 256, 0, stream>>>(src, Wvq, Wvk, Wvv, Qh, Kh, Vh, 0);
    k_attn<<<B_*NQT_, 256, 0, stream>>>(Qh, Kh, Vh, mask, ctx, att);
    k_outproj<<<(B_*S_)/16, 256, 0, stream>>>(ctx, WoT, bout, out);
    k_loss<<<1, 256, 0, stream>>>(partials, loss);
}

// Round 2
// 775.830 us; speedup vs baseline: 2.4034x; 2.4034x over previous
//
#include <hip/hip_runtime.h>
#include <math.h>

#define B_   16
#define S_   1056
#define DM_  256
#define H_   8
#define DK_  32
#define TXT_ 32
#define VID_ 1024
#define SS_  (S_*S_)          // 1115136
#define NQT_ 33               // q-tiles of 32 rows

#define LOG2_10000f 13.28771237954945f
#define LOG2_GAMMAf (-0.15200309344504995f)   // log2(0.9)
#define RSQRT_DKf   0.17677669529663687f      // 1/sqrt(32)
#define TWO_PIf     6.283185307179586f

typedef __attribute__((ext_vector_type(8))) short bf16x8;
typedef __attribute__((ext_vector_type(4))) float f32x4;

__device__ __forceinline__ short f2bf(float f){
    unsigned u = __float_as_uint(f);
    unsigned r = u + 0x7FFFu + ((u >> 16) & 1u);   // RNE
    return (short)(r >> 16);
}
__device__ __forceinline__ float bf2f(unsigned short s){
    return __uint_as_float(((unsigned)s) << 16);
}

// ---------------- mask + loss partials ----------------
__global__ __launch_bounds__(256) void k_mask(const float* __restrict__ lvr,
                       const int* __restrict__ row_idx, const int* __restrict__ col_idx,
                       float* __restrict__ mask, float* __restrict__ partials)
{
    int idx = blockIdx.x*256 + threadIdx.x;
    unsigned ui = (unsigned)idx;
    int i = ui / S_;
    int j = (int)(ui - (unsigned)i*S_);
    float vr, lm;
    if (i == j) { vr = 0.f; lm = 1.f; }
    else {
        float t = lvr[(size_t)row_idx[idx]*VID_ + col_idx[idx]];
        float sg = 1.f/(1.f + expf(-t));
        vr = sg; lm = sg;
    }
    float dmat = (i >= j) ? exp2f((float)(i-j)*LOG2_GAMMAf) : 0.f;
    mask[idx] = dmat * lm;
    float s = vr;
    #pragma unroll
    for (int m=1; m<64; m<<=1) s += __shfl_xor(s, m, 64);
    __shared__ float ws4[4];
    if ((threadIdx.x & 63) == 0) ws4[threadIdx.x>>6] = s;
    __syncthreads();
    if (threadIdx.x == 0) partials[blockIdx.x] = ws4[0]+ws4[1]+ws4[2]+ws4[3];
}

__global__ __launch_bounds__(256) void k_loss(const float* __restrict__ partials,
                                              float* __restrict__ out_loss)
{
    float s = 0.f;
    for (int i = threadIdx.x; i < SS_/256; i += 256) s += partials[i];
    #pragma unroll
    for (int m=1; m<64; m<<=1) s += __shfl_xor(s, m, 64);
    __shared__ float ws4[4];
    if ((threadIdx.x & 63) == 0) ws4[threadIdx.x>>6] = s;
    __syncthreads();
    if (threadIdx.x == 0) out_loss[0] = (ws4[0]+ws4[1]+ws4[2]+ws4[3]) * (1.f/(float)SS_);
}

// ---------------- W_out transpose ----------------
__global__ __launch_bounds__(256) void k_wot(const float* __restrict__ Wout,
                                             float* __restrict__ WoT)
{
    int t = blockIdx.x*256 + threadIdx.x;
    WoT[t] = Wout[(t & 255)*DM_ + (t >> 8)];
}

// ---------------- QKV projection (unchanged from R1, passing) ----------------
__global__ __launch_bounds__(256) void k_qkv(const float* __restrict__ src,
    const float* __restrict__ Wq, const float* __restrict__ Wk, const float* __restrict__ Wv,
    float* __restrict__ Qh, float* __restrict__ Kh, float* __restrict__ Vh, int is_txt)
{
    __shared__ float xt[3][DM_][20];
    int tid = threadIdx.x;
    int r0 = blockIdx.x * 16;
    int b, srow0;
    if (is_txt) { b = r0 >> 5;  srow0 = r0 & 31; }
    else        { b = r0 >> 10; srow0 = TXT_ + (r0 & 1023); }

    for (int it = 0; it < 8; ++it) {
        int task = it*256 + tid;
        int k  = task >> 4;
        int rr = task & 15;
        int srow = srow0 + rr;
        float2 x01 = ((const float2*)(src + ((size_t)b*S_ + srow)*DM_))[k];
        if (is_txt) {
            float xe  = (float)(srow + 1) * (TWO_PIf/(32.f + 1e-6f));
            float arg = xe * exp2f(-((float)k*(1.f/128.f))*LOG2_10000f);
            float p0 = sinf(arg), p1 = cosf(arg);
            xt[0][2*k  ][rr] = x01.x + p0;
            xt[0][2*k+1][rr] = x01.y + p1;
            xt[1][2*k  ][rr] = x01.x + p0;
            xt[1][2*k+1][rr] = x01.y + p1;
        } else {
            int l = srow - TXT_;
            float inv_freq = exp2f(-((float)k*(1.f/128.f))*LOG2_10000f);
            float arg = (float)l * inv_freq;
            float sn = sinf(arg), cs = cosf(arg);
            float base = ((float)(2*k) + 102.4f) * (1.f/358.4f);
            float scale = exp2f(((float)l*(1.f/512.f)) * log2f(base));
            float rsc = 1.f/scale;
            float y0 = x01.x*cs - x01.y*sn;
            float y1 = x01.y*cs + x01.x*sn;
            xt[0][2*k  ][rr] = y0*scale;  xt[0][2*k+1][rr] = y1*scale;
            xt[1][2*k  ][rr] = y0*rsc;    xt[1][2*k+1][rr] = y1*rsc;
        }
        xt[2][2*k  ][rr] = x01.x;
        xt[2][2*k+1][rr] = x01.y;
    }
    __syncthreads();

    int og = tid & 63, rg = tid >> 6;
    float aq[4][4], ak[4][4], av[4][4];
    #pragma unroll
    for (int c=0;c<4;c++)
      #pragma unroll
      for (int jr=0;jr<4;jr++){ aq[c][jr]=0.f; ak[c][jr]=0.f; av[c][jr]=0.f; }

    for (int e = 0; e < DM_; ++e) {
        float4 xq = *(const float4*)&xt[0][e][rg*4];
        float4 xk = *(const float4*)&xt[1][e][rg*4];
        float4 xv = *(const float4*)&xt[2][e][rg*4];
        float4 wq = *(const float4*)&Wq[e*DM_ + og*4];
        float4 wk = *(const float4*)&Wk[e*DM_ + og*4];
        float4 wv = *(const float4*)&Wv[e*DM_ + og*4];
        float xqa[4] = {xq.x,xq.y,xq.z,xq.w};
        float xka[4] = {xk.x,xk.y,xk.z,xk.w};
        float xva[4] = {xv.x,xv.y,xv.z,xv.w};
        #pragma unroll
        for (int jr=0;jr<4;jr++){
            aq[0][jr] = fmaf(xqa[jr], wq.x, aq[0][jr]);
            aq[1][jr] = fmaf(xqa[jr], wq.y, aq[1][jr]);
            aq[2][jr] = fmaf(xqa[jr], wq.z, aq[2][jr]);
            aq[3][jr] = fmaf(xqa[jr], wq.w, aq[3][jr]);
            ak[0][jr] = fmaf(xka[jr], wk.x, ak[0][jr]);
            ak[1][jr] = fmaf(xka[jr], wk.y, ak[1][jr]);
            ak[2][jr] = fmaf(xka[jr], wk.z, ak[2][jr]);
            ak[3][jr] = fmaf(xka[jr], wk.w, ak[3][jr]);
            av[0][jr] = fmaf(xva[jr], wv.x, av[0][jr]);
            av[1][jr] = fmaf(xva[jr], wv.y, av[1][jr]);
            av[2][jr] = fmaf(xva[jr], wv.z, av[2][jr]);
            av[3][jr] = fmaf(xva[jr], wv.w, av[3][jr]);
        }
    }
    int head = og >> 3;
    int dbase = (og & 7) * 4;
    #pragma unroll
    for (int jr=0;jr<4;jr++){
        int srow = srow0 + rg*4 + jr;
        size_t off = ((size_t)(b*H_ + head)*S_ + srow)*DK_ + dbase;
        float4 q4 = make_float4(aq[0][jr]*RSQRT_DKf, aq[1][jr]*RSQRT_DKf,
                                aq[2][jr]*RSQRT_DKf, aq[3][jr]*RSQRT_DKf);
        float4 k4 = make_float4(ak[0][jr], ak[1][jr], ak[2][jr], ak[3][jr]);
        float4 v4 = make_float4(av[0][jr], av[1][jr], av[2][jr], av[3][jr]);
        *(float4*)&Qh[off] = q4;
        *(float4*)&Kh[off] = k4;
        *(float4*)&Vh[off] = v4;
    }
}

// ---------------- MFMA attention ----------------
// block = (b, 32-row q-tile), 512 threads = 8 waves, loops all 8 heads.
// QK^T: S^T(k,q) tiles = mfma(A=K_tile, B=Q^T)  [D: col=lane&15 -> q, rows -> k]
// PV  : ctx(q,d)      = mfma(A=P_tile, B=Vt)    [D: col=lane&15 -> d, rows -> q]
#define PPAD 1064      // P row stride (bf16 elems), 16B-aligned, bank-friendly
#define KPAD 40        // K tile row stride
#define VTPAD 72       // Vt row stride

__global__ __launch_bounds__(512, 4) void k_attn(const float* __restrict__ Qh,
    const float* __restrict__ Kh, const float* __restrict__ Vh,
    const float* __restrict__ mask, float* __restrict__ ctx, float* __restrict__ att)
{
    __shared__ __align__(16) short P[32][PPAD];       // e values, bf16: 68.1 KB
    __shared__ __align__(16) short K2[2][64][KPAD];   // K staging / Vt staging: 10.2 KB
    __shared__ float rs[2][16][4];
    __shared__ float denom_l[32];

    int tid  = threadIdx.x;
    int lane = tid & 63;
    int w    = tid >> 6;          // wave 0..7
    int b    = blockIdx.x / NQT_;
    int qt   = blockIdx.x - b*NQT_;
    int q0   = qt * 32;

    int lr = lane & 15;           // in-tile row/col
    int lg = lane >> 4;           // 0..3

    // QK roles
    int qh_qk = w >> 2;           // q-half (0/1)
    int ksub  = w & 3;            // 16-col subtile of 64-k tile
    // PV roles
    int qh_pv = w & 1;
    int dh_pv = (w >> 1) & 1;
    int kh_pv = w >> 2;           // k-half of 64-k tile

    // att accumulators: thread owns q = tid>>4, k = 4*(tid&15) + 64*c + j
    int aq  = tid >> 4;           // 0..31
    int ak0 = 4 * (tid & 15);
    float attacc[17][4];
    #pragma unroll
    for (int c=0;c<17;c++){ attacc[c][0]=0.f; attacc[c][1]=0.f; attacc[c][2]=0.f; attacc[c][3]=0.f; }

    for (int h = 0; h < H_; ++h) {
        const float* Qbh = Qh + ((size_t)(b*H_+h)*S_ + q0)*DK_;
        const float* Kbh = Kh + (size_t)(b*H_+h)*S_*DK_;
        const float* Vbh = Vh + (size_t)(b*H_+h)*S_*DK_;

        // Q B-fragment (this wave's q-half): col=q (lr), k-dim dk = lg*8..+7
        bf16x8 qfrag;
        {
            const float* qrow = Qbh + (size_t)(qh_qk*16 + lr)*DK_ + lg*8;
            float4 a = *(const float4*)qrow;
            float4 c = *(const float4*)(qrow+4);
            qfrag[0]=f2bf(a.x); qfrag[1]=f2bf(a.y); qfrag[2]=f2bf(a.z); qfrag[3]=f2bf(a.w);
            qfrag[4]=f2bf(c.x); qfrag[5]=f2bf(c.y); qfrag[6]=f2bf(c.z); qfrag[7]=f2bf(c.w);
        }

        // ---- phase 1: S^T + exp, stream k in 64-tiles ----
        float rssum = 0.f;
        for (int t = 0; t < 17; ++t) {
            int kb0  = t*64;
            int rows = (kb0 + 64 <= S_) ? 64 : (S_ - kb0);   // 64 or 32
            {   // stage K tile (fp32 -> bf16), one float4 per thread
                int kk = tid >> 3;
                int d4 = (tid & 7) * 4;
                if (kk < rows) {
                    float4 kv = *(const float4*)(Kbh + (size_t)(kb0+kk)*DK_ + d4);
                    short4 s4; s4.x=f2bf(kv.x); s4.y=f2bf(kv.y); s4.z=f2bf(kv.z); s4.w=f2bf(kv.w);
                    *(short4*)&K2[t&1][kk][d4] = s4;
                }
            }
            __syncthreads();
            if (ksub*16 < rows) {
                bf16x8 af = *(const bf16x8*)&K2[t&1][ksub*16 + lr][lg*8];
                f32x4 acc = {0.f,0.f,0.f,0.f};
                acc = __builtin_amdgcn_mfma_f32_16x16x32_bf16(af, qfrag, acc, 0, 0, 0);
                // lane: q = q0 + qh_qk*16 + lr ; k rows = kb0 + ksub*16 + lg*4 + reg
                int qq = q0 + qh_qk*16 + lr;
                int kk = kb0 + ksub*16 + lg*4;
                float4 m4 = *(const float4*)(mask + (size_t)qq*S_ + kk);
                float e0 = __expf(acc.x * m4.x);
                float e1 = __expf(acc.y * m4.y);
                float e2 = __expf(acc.z * m4.z);
                float e3 = __expf(acc.w * m4.w);
                rssum += (e0+e1) + (e2+e3);
                short4 s4; s4.x=f2bf(e0); s4.y=f2bf(e1); s4.z=f2bf(e2); s4.w=f2bf(e3);
                *(short4*)&P[qh_qk*16 + lr][kk] = s4;
            }
        }
        // ---- phase 2: denominators ----
        rssum += __shfl_xor(rssum, 16, 64);
        rssum += __shfl_xor(rssum, 32, 64);
        if (lane < 16) rs[qh_qk][lr][ksub] = rssum;
        __syncthreads();
        if (tid < 32) {
            float s = rs[tid>>4][tid&15][0] + rs[tid>>4][tid&15][1]
                    + rs[tid>>4][tid&15][2] + rs[tid>>4][tid&15][3];
            denom_l[tid] = 1.f/s;
        }
        __syncthreads();

        // ---- phase 3a: att accumulation (fixed lane->(q,k) map across heads) ----
        {
            float rd = denom_l[aq] * 0.125f;
            #pragma unroll
            for (int c = 0; c < 17; ++c) {
                int k = ak0 + 64*c;
                if (c < 16 || ak0 < 32) {
                    ushort4 pv = *(const ushort4*)&P[aq][k];
                    attacc[c][0] = fmaf(bf2f(pv.x), rd, attacc[c][0]);
                    attacc[c][1] = fmaf(bf2f(pv.y), rd, attacc[c][1]);
                    attacc[c][2] = fmaf(bf2f(pv.z), rd, attacc[c][2]);
                    attacc[c][3] = fmaf(bf2f(pv.w), rd, attacc[c][3]);
                }
            }
        }

        // ---- phase 3b: PV ----
        f32x4 pvacc = {0.f,0.f,0.f,0.f};
        for (int t = 0; t < 17; ++t) {
            int kb0  = t*64;
            int rows = (kb0 + 64 <= S_) ? 64 : (S_ - kb0);
            short* vt = &K2[t&1][0][0];   // reinterpreted as Vt[32][VTPAD]
            {   // transpose-stage V tile (fp32 -> bf16)
                int kk = tid >> 3;
                int d4 = (tid & 7) * 4;
                if (kk < rows) {
                    float4 vv = *(const float4*)(Vbh + (size_t)(kb0+kk)*DK_ + d4);
                    vt[(d4+0)*VTPAD + kk] = f2bf(vv.x);
                    vt[(d4+1)*VTPAD + kk] = f2bf(vv.y);
                    vt[(d4+2)*VTPAD + kk] = f2bf(vv.z);
                    vt[(d4+3)*VTPAD + kk] = f2bf(vv.w);
                }
            }
            __syncthreads();
            int klocal = kh_pv * 32;
            if (klocal < rows) {
                bf16x8 af = *(const bf16x8*)&P[qh_pv*16 + lr][kb0 + klocal + lg*8];
                bf16x8 bfv = *(const bf16x8*)&vt[(dh_pv*16 + lr)*VTPAD + klocal + lg*8];
                pvacc = __builtin_amdgcn_mfma_f32_16x16x32_bf16(af, bfv, pvacc, 0, 0, 0);
            }
        }
        __syncthreads();
        // ---- phase 3c: reduce k-halves (ctx_red aliased onto P) + writeout ----
        float* ctx_red = (float*)&P[0][0];    // [32][36]
        if (kh_pv == 1) {
            #pragma unroll
            for (int r = 0; r < 4; ++r) {
                int qq = qh_pv*16 + lg*4 + r;
                int dd = dh_pv*16 + lr;
                ctx_red[qq*36 + dd] = pvacc[r];
            }
        }
        __syncthreads();
        if (kh_pv == 0) {
            #pragma unroll
            for (int r = 0; r < 4; ++r) {
                int qq = qh_pv*16 + lg*4 + r;
                int dd = dh_pv*16 + lr;
                float v = pvacc[r] + ctx_red[qq*36 + dd];
                ctx[((size_t)b*S_ + q0+qq)*DM_ + h*DK_ + dh_pv*16 + lr] = v * denom_l[qq];
            }
        }
        __syncthreads();   // before next head rewrites P / K2
    }

    // ---- att writeout ----
    #pragma unroll
    for (int c = 0; c < 17; ++c) {
        int k = ak0 + 64*c;
        if (c < 16 || ak0 < 32) {
            float4 o4 = make_float4(attacc[c][0], attacc[c][1], attacc[c][2], attacc[c][3]);
            *(float4*)&att[((size_t)b*S_ + q0+aq)*S_ + k] = o4;
        }
    }
}

// ---------------- out projection ----------------
__global__ __launch_bounds__(256) void k_outproj(const float* __restrict__ ctxp,
    const float* __restrict__ WoT, const float* __restrict__ bias, float* __restrict__ out)
{
    __shared__ float ct[DM_][20];
    int tid = threadIdx.x;
    int r0 = blockIdx.x * 16;
    for (int it = 0; it < 16; ++it) {
        int task = it*256 + tid;
        int col = task >> 4;
        int rr  = task & 15;
        ct[col][rr] = ctxp[(size_t)(r0+rr)*DM_ + col];
    }
    __syncthreads();
    int og = tid & 63, rg = tid >> 6;
    float acc[4][4];
    #pragma unroll
    for (int c=0;c<4;c++)
      #pragma unroll
      for (int jr=0;jr<4;jr++) acc[c][jr] = 0.f;
    for (int e = 0; e < DM_; ++e){
        float4 x4 = *(const float4*)&ct[e][rg*4];
        float4 w4 = *(const float4*)&WoT[e*DM_ + og*4];
        float xa[4] = {x4.x,x4.y,x4.z,x4.w};
        #pragma unroll
        for (int jr=0;jr<4;jr++){
            acc[0][jr] = fmaf(xa[jr], w4.x, acc[0][jr]);
            acc[1][jr] = fmaf(xa[jr], w4.y, acc[1][jr]);
            acc[2][jr] = fmaf(xa[jr], w4.z, acc[2][jr]);
            acc[3][jr] = fmaf(xa[jr], w4.w, acc[3][jr]);
        }
    }
    float4 b4 = *(const float4*)&bias[og*4];
    #pragma unroll
    for (int jr=0;jr<4;jr++){
        int r = r0 + rg*4 + jr;
        float4 o4 = make_float4(acc[0][jr]+b4.x, acc[1][jr]+b4.y,
                                acc[2][jr]+b4.z, acc[3][jr]+b4.w);
        *(float4*)&out[(size_t)r*DM_ + og*4] = o4;
    }
}

extern "C" void kernel_launch(void* const* d_in, const int* in_sizes, int n_in,
                              void* d_out, int out_size, void* d_ws, size_t ws_size,
                              hipStream_t stream)
{
    (void)in_sizes; (void)n_in; (void)out_size; (void)ws_size;
    const float* src  = (const float*)d_in[0];
    const float* Wtq  = (const float*)d_in[1];
    const float* Wtk  = (const float*)d_in[2];
    const float* Wtv  = (const float*)d_in[3];
    const float* Wvq  = (const float*)d_in[4];
    const float* Wvk  = (const float*)d_in[5];
    const float* Wvv  = (const float*)d_in[6];
    const float* lvr  = (const float*)d_in[7];
    const float* Wout = (const float*)d_in[8];
    const float* bout = (const float*)d_in[9];
    const int*   rid  = (const int*)d_in[10];
    const int*   cid  = (const int*)d_in[11];

    const size_t QKV_SZ = (size_t)B_*H_*S_*DK_;
    float* ws       = (float*)d_ws;
    float* mask     = ws;
    float* Qh       = mask + SS_;
    float* Kh       = Qh + QKV_SZ;
    float* Vh       = Kh + QKV_SZ;
    float* ctx      = Vh + QKV_SZ;
    float* WoT      = ctx + (size_t)B_*S_*DM_;
    float* partials = WoT + DM_*DM_;

    float* out  = (float*)d_out;
    float* att  = out + (size_t)B_*S_*DM_;
    float* loss = att + (size_t)B_*S_*S_;

    k_mask<<<SS_/256, 256, 0, stream>>>(lvr, rid, cid, mask, partials);
    k_wot<<<DM_*DM_/256, 256, 0, stream>>>(Wout, WoT);
    k_qkv<<<(B_*TXT_)/16, 256, 0, stream>>>(src, Wtq, Wtk, Wtv, Qh, Kh, Vh, 1);
    k_qkv<<<(B_*VID_)/16, 256, 0, stream>>>(src, Wvq, Wvk, Wvv, Qh, Kh, Vh, 0);
    k_attn<<<B_*NQT_, 512, 0, stream>>>(Qh, Kh, Vh, mask, ctx, att);
    k_outproj<<<(B_*S_)/16, 256, 0, stream>>>(ctx, WoT, bout, out);
    k_loss<<<1, 256, 0, stream>>>(partials, loss);
}

// Round 3
// 594.295 us; speedup vs baseline: 3.1376x; 1.3055x over previous
//
#include <hip/hip_runtime.h>
#include <math.h>

#define B_   16
#define S_   1056
#define SP_  1088             // k padded to 34*32
#define DM_  256
#define H_   8
#define DK_  32
#define TXT_ 32
#define VID_ 1024
#define SS_  (S_*S_)          // 1115136
#define NQT_ 66               // q-tiles of 16 rows

#define LOG2_10000f 13.28771237954945f
#define LOG2_GAMMAf (-0.15200309344504995f)   // log2(0.9)
#define RSQRT_DKf   0.17677669529663687f      // 1/sqrt(32)
#define TWO_PIf     6.283185307179586f

typedef __attribute__((ext_vector_type(8))) short bf16x8;
typedef __attribute__((ext_vector_type(4))) float f32x4;

__device__ __forceinline__ short f2bf(float f){
    unsigned u = __float_as_uint(f);
    unsigned r = u + 0x7FFFu + ((u >> 16) & 1u);   // RNE
    return (short)(r >> 16);
}
__device__ __forceinline__ float bf2f(unsigned short s){
    return __uint_as_float(((unsigned)s) << 16);
}

// ---------------- mask + loss partials ----------------
__global__ __launch_bounds__(256) void k_mask(const float* __restrict__ lvr,
                       const int* __restrict__ row_idx, const int* __restrict__ col_idx,
                       float* __restrict__ mask, float* __restrict__ partials)
{
    int idx = blockIdx.x*256 + threadIdx.x;
    unsigned ui = (unsigned)idx;
    int i = ui / S_;
    int j = (int)(ui - (unsigned)i*S_);
    float vr, lm;
    if (i == j) { vr = 0.f; lm = 1.f; }
    else {
        float t = lvr[(size_t)row_idx[idx]*VID_ + col_idx[idx]];
        float sg = 1.f/(1.f + expf(-t));
        vr = sg; lm = sg;
    }
    float dmat = (i >= j) ? exp2f((float)(i-j)*LOG2_GAMMAf) : 0.f;
    mask[idx] = dmat * lm;
    float s = vr;
    #pragma unroll
    for (int m=1; m<64; m<<=1) s += __shfl_xor(s, m, 64);
    __shared__ float ws4[4];
    if ((threadIdx.x & 63) == 0) ws4[threadIdx.x>>6] = s;
    __syncthreads();
    if (threadIdx.x == 0) partials[blockIdx.x] = ws4[0]+ws4[1]+ws4[2]+ws4[3];
}

__global__ __launch_bounds__(256) void k_loss(const float* __restrict__ partials,
                                              float* __restrict__ out_loss)
{
    float s = 0.f;
    for (int i = threadIdx.x; i < SS_/256; i += 256) s += partials[i];
    #pragma unroll
    for (int m=1; m<64; m<<=1) s += __shfl_xor(s, m, 64);
    __shared__ float ws4[4];
    if ((threadIdx.x & 63) == 0) ws4[threadIdx.x>>6] = s;
    __syncthreads();
    if (threadIdx.x == 0) out_loss[0] = (ws4[0]+ws4[1]+ws4[2]+ws4[3]) * (1.f/(float)SS_);
}

// ---------------- W_out transpose ----------------
__global__ __launch_bounds__(256) void k_wot(const float* __restrict__ Wout,
                                             float* __restrict__ WoT)
{
    int t = blockIdx.x*256 + threadIdx.x;
    WoT[t] = Wout[(t & 255)*DM_ + (t >> 8)];
}

// ---------------- QKV projection -> bf16 Q,K row-major + bf16 V^T ----------------
__global__ __launch_bounds__(256) void k_qkv(const float* __restrict__ src,
    const float* __restrict__ Wq, const float* __restrict__ Wk, const float* __restrict__ Wv,
    short* __restrict__ Qb, short* __restrict__ Kb, short* __restrict__ VT, int is_txt)
{
    __shared__ float xt[3][DM_][20];
    __shared__ __align__(16) short vt16[DM_][24];
    int tid = threadIdx.x;
    int r0 = blockIdx.x * 16;
    int b, srow0;
    if (is_txt) { b = r0 >> 5;  srow0 = r0 & 31; }
    else        { b = r0 >> 10; srow0 = TXT_ + (r0 & 1023); }

    for (int it = 0; it < 8; ++it) {
        int task = it*256 + tid;
        int k  = task >> 4;
        int rr = task & 15;
        int srow = srow0 + rr;
        float2 x01 = ((const float2*)(src + ((size_t)b*S_ + srow)*DM_))[k];
        if (is_txt) {
            float xe  = (float)(srow + 1) * (TWO_PIf/(32.f + 1e-6f));
            float arg = xe * exp2f(-((float)k*(1.f/128.f))*LOG2_10000f);
            float p0 = sinf(arg), p1 = cosf(arg);
            xt[0][2*k  ][rr] = x01.x + p0;
            xt[0][2*k+1][rr] = x01.y + p1;
            xt[1][2*k  ][rr] = x01.x + p0;
            xt[1][2*k+1][rr] = x01.y + p1;
        } else {
            int l = srow - TXT_;
            float inv_freq = exp2f(-((float)k*(1.f/128.f))*LOG2_10000f);
            float arg = (float)l * inv_freq;
            float sn = sinf(arg), cs = cosf(arg);
            float base = ((float)(2*k) + 102.4f) * (1.f/358.4f);
            float scale = exp2f(((float)l*(1.f/512.f)) * log2f(base));
            float rsc = 1.f/scale;
            float y0 = x01.x*cs - x01.y*sn;
            float y1 = x01.y*cs + x01.x*sn;
            xt[0][2*k  ][rr] = y0*scale;  xt[0][2*k+1][rr] = y1*scale;
            xt[1][2*k  ][rr] = y0*rsc;    xt[1][2*k+1][rr] = y1*rsc;
        }
        xt[2][2*k  ][rr] = x01.x;
        xt[2][2*k+1][rr] = x01.y;
    }
    __syncthreads();

    int og = tid & 63, rg = tid >> 6;
    float aq[4][4], ak[4][4], av[4][4];
    #pragma unroll
    for (int c=0;c<4;c++)
      #pragma unroll
      for (int jr=0;jr<4;jr++){ aq[c][jr]=0.f; ak[c][jr]=0.f; av[c][jr]=0.f; }

    for (int e = 0; e < DM_; ++e) {
        float4 xq = *(const float4*)&xt[0][e][rg*4];
        float4 xk = *(const float4*)&xt[1][e][rg*4];
        float4 xv = *(const float4*)&xt[2][e][rg*4];
        float4 wq = *(const float4*)&Wq[e*DM_ + og*4];
        float4 wk = *(const float4*)&Wk[e*DM_ + og*4];
        float4 wv = *(const float4*)&Wv[e*DM_ + og*4];
        float xqa[4] = {xq.x,xq.y,xq.z,xq.w};
        float xka[4] = {xk.x,xk.y,xk.z,xk.w};
        float xva[4] = {xv.x,xv.y,xv.z,xv.w};
        #pragma unroll
        for (int jr=0;jr<4;jr++){
            aq[0][jr] = fmaf(xqa[jr], wq.x, aq[0][jr]);
            aq[1][jr] = fmaf(xqa[jr], wq.y, aq[1][jr]);
            aq[2][jr] = fmaf(xqa[jr], wq.z, aq[2][jr]);
            aq[3][jr] = fmaf(xqa[jr], wq.w, aq[3][jr]);
            ak[0][jr] = fmaf(xka[jr], wk.x, ak[0][jr]);
            ak[1][jr] = fmaf(xka[jr], wk.y, ak[1][jr]);
            ak[2][jr] = fmaf(xka[jr], wk.z, ak[2][jr]);
            ak[3][jr] = fmaf(xka[jr], wk.w, ak[3][jr]);
            av[0][jr] = fmaf(xva[jr], wv.x, av[0][jr]);
            av[1][jr] = fmaf(xva[jr], wv.y, av[1][jr]);
            av[2][jr] = fmaf(xva[jr], wv.z, av[2][jr]);
            av[3][jr] = fmaf(xva[jr], wv.w, av[3][jr]);
        }
    }
    int head = og >> 3;
    int dbase = (og & 7) * 4;
    #pragma unroll
    for (int jr=0;jr<4;jr++){
        int srow = srow0 + rg*4 + jr;
        size_t off = ((size_t)(b*H_ + head)*S_ + srow)*DK_ + dbase;
        short4 q4; q4.x=f2bf(aq[0][jr]*RSQRT_DKf); q4.y=f2bf(aq[1][jr]*RSQRT_DKf);
                   q4.z=f2bf(aq[2][jr]*RSQRT_DKf); q4.w=f2bf(aq[3][jr]*RSQRT_DKf);
        short4 k4; k4.x=f2bf(ak[0][jr]); k4.y=f2bf(ak[1][jr]);
                   k4.z=f2bf(ak[2][jr]); k4.w=f2bf(ak[3][jr]);
        *(short4*)&Qb[off] = q4;
        *(short4*)&Kb[off] = k4;
        #pragma unroll
        for (int c=0;c<4;c++) vt16[og*4+c][rg*4+jr] = f2bf(av[c][jr]);
    }
    __syncthreads();
    // VT writeout: thread tid owns out-dim column `tid` = head (tid>>5), d (tid&31)
    {
        bf16x8 v0 = *(const bf16x8*)&vt16[tid][0];
        bf16x8 v1 = *(const bf16x8*)&vt16[tid][8];
        size_t vtoff = ((size_t)(b*H_ + (tid>>5))*DK_ + (tid&31))*SP_ + srow0;
        *(bf16x8*)&VT[vtoff]     = v0;
        *(bf16x8*)&VT[vtoff + 8] = v1;
    }
}

// ---------------- MFMA attention, barrier-light ----------------
// block = (b, 16-row q-tile), 256 threads = 4 waves, loops all 8 heads.
// QK^T: mfma(A=K_16k_x_32dk [global bf16], B=Q^T) -> D col=q, rows=k
// PV  : mfma(A=P_16q_x_32k [LDS, swizzled], B=V^T slice [global bf16]) -> D row=q, col=d
#define PPAD 1096     // P row stride in shorts (548 dwords, %32==4)

__global__ __launch_bounds__(256, 3) void k_attn(const short* __restrict__ Qb,
    const short* __restrict__ Kb, const short* __restrict__ VT,
    const float* __restrict__ mask, float* __restrict__ ctx, float* __restrict__ att)
{
    __shared__ __align__(16) short P[16][PPAD];   // 34.3 KB, XOR-swizzled columns
    __shared__ float rs[4][16];
    __shared__ float denom_l[16];
    __shared__ float pv_red[16][36];

    int tid  = threadIdx.x;
    int lane = tid & 63;
    int w    = tid >> 6;          // wave 0..3
    int b    = blockIdx.x & 15;   // qt-major grid: same-qt blocks adjacent (mask L2 reuse)
    int qt   = blockIdx.x >> 4;
    int q0   = qt * 16;

    int lr = lane & 15;
    int lg = lane >> 4;
    int dh = w & 1;               // PV d-half
    int kh = w >> 1;              // PV k-half

    int aq  = tid >> 4;           // att row 0..15
    int ak0 = 4 * (tid & 15);
    int swa = (aq & 7) << 3;      // att-pass column swizzle
    int swq = (lr & 7) << 3;      // PV A-read / phase1-write swizzle (row = lr)

    f32x4 attacc[17];
    #pragma unroll
    for (int c=0;c<17;c++){ attacc[c][0]=0.f; attacc[c][1]=0.f; attacc[c][2]=0.f; attacc[c][3]=0.f; }

    for (int h = 0; h < H_; ++h) {
        const short* Qp = Qb + ((size_t)(b*H_+h)*S_ + q0)*DK_;
        const short* Kp = Kb + (size_t)(b*H_+h)*S_*DK_;
        bf16x8 qfrag = *(const bf16x8*)(Qp + lr*DK_ + lg*8);

        // ---- phase 1: scores + exp -> P (no barriers inside) ----
        float rssum = 0.f;
        #pragma unroll
        for (int t = 0; t < 17; ++t) {
            int k0 = t*64 + w*16;
            int colbase = k0 + lg*4;
            short4 s4;
            if (k0 < S_) {
                bf16x8 kf = *(const bf16x8*)(Kp + (size_t)(k0+lr)*DK_ + lg*8);
                f32x4 acc = {0.f,0.f,0.f,0.f};
                acc = __builtin_amdgcn_mfma_f32_16x16x32_bf16(kf, qfrag, acc, 0, 0, 0);
                float4 m4 = *(const float4*)(mask + (size_t)(q0+lr)*S_ + colbase);
                float e0 = __expf(acc[0]*m4.x);
                float e1 = __expf(acc[1]*m4.y);
                float e2 = __expf(acc[2]*m4.z);
                float e3 = __expf(acc[3]*m4.w);
                rssum += (e0+e1) + (e2+e3);
                s4.x=f2bf(e0); s4.y=f2bf(e1); s4.z=f2bf(e2); s4.w=f2bf(e3);
            } else {
                s4.x=0; s4.y=0; s4.z=0; s4.w=0;
            }
            *(short4*)&P[lr][colbase ^ swq] = s4;
        }
        // ---- denominators ----
        rssum += __shfl_xor(rssum, 16, 64);
        rssum += __shfl_xor(rssum, 32, 64);
        if (lane < 16) rs[w][lr] = rssum;
        __syncthreads();
        if (tid < 16) denom_l[tid] = 1.f/(rs[0][tid]+rs[1][tid]+rs[2][tid]+rs[3][tid]);
        __syncthreads();

        // ---- att accumulation (branch-free; P zero-padded) ----
        {
            float rd = denom_l[aq] * 0.125f;
            #pragma unroll
            for (int c = 0; c < 17; ++c) {
                ushort4 pv = *(const ushort4*)&P[aq][(ak0 + 64*c) ^ swa];
                attacc[c][0] = fmaf(bf2f(pv.x), rd, attacc[c][0]);
                attacc[c][1] = fmaf(bf2f(pv.y), rd, attacc[c][1]);
                attacc[c][2] = fmaf(bf2f(pv.z), rd, attacc[c][2]);
                attacc[c][3] = fmaf(bf2f(pv.w), rd, attacc[c][3]);
            }
        }

        // ---- PV: wave owns (dh, kh); 17 k-tiles of 32 each ----
        const short* Vp = VT + ((size_t)(b*H_+h)*DK_ + dh*16 + lr)*SP_;
        f32x4 pvacc = {0.f,0.f,0.f,0.f};
        #pragma unroll
        for (int t2 = 0; t2 < 17; ++t2) {
            int kb = (kh*17 + t2)*32;
            bf16x8 pf = *(const bf16x8*)&P[lr][(kb + lg*8) ^ swq];
            bf16x8 vf = *(const bf16x8*)(Vp + kb + lg*8);
            pvacc = __builtin_amdgcn_mfma_f32_16x16x32_bf16(pf, vf, pvacc, 0, 0, 0);
        }
        if (kh == 1) {
            #pragma unroll
            for (int r = 0; r < 4; ++r) pv_red[lg*4+r][dh*16+lr] = pvacc[r];
        }
        __syncthreads();
        if (kh == 0) {
            #pragma unroll
            for (int r = 0; r < 4; ++r) {
                int qq = lg*4 + r;
                float v = pvacc[r] + pv_red[qq][dh*16+lr];
                ctx[((size_t)b*S_ + q0+qq)*DM_ + h*DK_ + dh*16 + lr] = v * denom_l[qq];
            }
        }
        __syncthreads();   // P, rs, denom_l, pv_red free for next head
    }

    // ---- att writeout ----
    #pragma unroll
    for (int c = 0; c < 17; ++c) {
        if (c < 16 || ak0 < 32) {
            float4 o4 = make_float4(attacc[c][0], attacc[c][1], attacc[c][2], attacc[c][3]);
            *(float4*)&att[((size_t)b*S_ + q0+aq)*S_ + ak0 + 64*c] = o4;
        }
    }
}

// ---------------- out projection ----------------
__global__ __launch_bounds__(256) void k_outproj(const float* __restrict__ ctxp,
    const float* __restrict__ WoT, const float* __restrict__ bias, float* __restrict__ out)
{
    __shared__ float ct[DM_][20];
    int tid = threadIdx.x;
    int r0 = blockIdx.x * 16;
    for (int it = 0; it < 16; ++it) {
        int task = it*256 + tid;
        int col = task >> 4;
        int rr  = task & 15;
        ct[col][rr] = ctxp[(size_t)(r0+rr)*DM_ + col];
    }
    __syncthreads();
    int og = tid & 63, rg = tid >> 6;
    float acc[4][4];
    #pragma unroll
    for (int c=0;c<4;c++)
      #pragma unroll
      for (int jr=0;jr<4;jr++) acc[c][jr] = 0.f;
    for (int e = 0; e < DM_; ++e){
        float4 x4 = *(const float4*)&ct[e][rg*4];
        float4 w4 = *(const float4*)&WoT[e*DM_ + og*4];
        float xa[4] = {x4.x,x4.y,x4.z,x4.w};
        #pragma unroll
        for (int jr=0;jr<4;jr++){
            acc[0][jr] = fmaf(xa[jr], w4.x, acc[0][jr]);
            acc[1][jr] = fmaf(xa[jr], w4.y, acc[1][jr]);
            acc[2][jr] = fmaf(xa[jr], w4.z, acc[2][jr]);
            acc[3][jr] = fmaf(xa[jr], w4.w, acc[3][jr]);
        }
    }
    float4 b4 = *(const float4*)&bias[og*4];
    #pragma unroll
    for (int jr=0;jr<4;jr++){
        int r = r0 + rg*4 + jr;
        float4 o4 = make_float4(acc[0][jr]+b4.x, acc[1][jr]+b4.y,
                                acc[2][jr]+b4.z, acc[3][jr]+b4.w);
        *(float4*)&out[(size_t)r*DM_ + og*4] = o4;
    }
}

extern "C" void kernel_launch(void* const* d_in, const int* in_sizes, int n_in,
                              void* d_out, int out_size, void* d_ws, size_t ws_size,
                              hipStream_t stream)
{
    (void)in_sizes; (void)n_in; (void)out_size; (void)ws_size;
    const float* src  = (const float*)d_in[0];
    const float* Wtq  = (const float*)d_in[1];
    const float* Wtk  = (const float*)d_in[2];
    const float* Wtv  = (const float*)d_in[3];
    const float* Wvq  = (const float*)d_in[4];
    const float* Wvk  = (const float*)d_in[5];
    const float* Wvv  = (const float*)d_in[6];
    const float* lvr  = (const float*)d_in[7];
    const float* Wout = (const float*)d_in[8];
    const float* bout = (const float*)d_in[9];
    const int*   rid  = (const int*)d_in[10];
    const int*   cid  = (const int*)d_in[11];

    const size_t QKV_SH = (size_t)B_*H_*S_*DK_;    // shorts per Q/K buffer
    const size_t VT_SH  = (size_t)B_*H_*DK_*SP_;   // shorts for V^T

    float* ws       = (float*)d_ws;
    float* mask     = ws;                           // SS_
    float* ctx      = mask + SS_;                   // B*S*DM
    float* WoT      = ctx + (size_t)B_*S_*DM_;      // 65536
    float* partials = WoT + DM_*DM_;                // 4356
    short* Qb       = (short*)(partials + 4356);
    short* Kb       = Qb + QKV_SH;
    short* VT       = Kb + QKV_SH;
    (void)VT_SH;

    float* out  = (float*)d_out;
    float* att  = out + (size_t)B_*S_*DM_;
    float* loss = att + (size_t)B_*S_*S_;

    k_mask<<<SS_/256, 256, 0, stream>>>(lvr, rid, cid, mask, partials);
    k_wot<<<DM_*DM_/256, 256, 0, stream>>>(Wout, WoT);
    k_qkv<<<(B_*TXT_)/16, 256, 0, stream>>>(src, Wtq, Wtk, Wtv, Qb, Kb, VT, 1);
    k_qkv<<<(B_*VID_)/16, 256, 0, stream>>>(src, Wvq, Wvk, Wvv, Qb, Kb, VT, 0);
    k_attn<<<B_*NQT_, 256, 0, stream>>>(Qb, Kb, VT, mask, ctx, att);
    k_outproj<<<(B_*S_)/16, 256, 0, stream>>>(ctx, WoT, bout, out);
    k_loss<<<1, 256, 0, stream>>>(partials, loss);
}

// Round 4
// 589.193 us; speedup vs baseline: 3.1648x; 1.0087x over previous
//
#include <hip/hip_runtime.h>
#include <math.h>

#define B_   16
#define S_   1056
#define SP_  1088             // k padded to 34*32
#define DM_  256
#define H_   8
#define DK_  32
#define TXT_ 32
#define VID_ 1024
#define SS_  (S_*S_)          // 1115136
#define NQT_ 66               // q-tiles of 16 rows

#define LOG2_10000f 13.28771237954945f
#define LOG2_GAMMAf (-0.15200309344504995f)   // log2(0.9)
#define RSQRT_DKf   0.17677669529663687f      // 1/sqrt(32)
#define TWO_PIf     6.283185307179586f

typedef __attribute__((ext_vector_type(8))) short bf16x8;
typedef __attribute__((ext_vector_type(4))) float f32x4;

__device__ __forceinline__ short f2bf(float f){
    unsigned u = __float_as_uint(f);
    unsigned r = u + 0x7FFFu + ((u >> 16) & 1u);   // RNE
    return (short)(r >> 16);
}
__device__ __forceinline__ float bf2f(unsigned short s){
    return __uint_as_float(((unsigned)s) << 16);
}

// ---------------- mask + loss partials ----------------
__global__ __launch_bounds__(256) void k_mask(const float* __restrict__ lvr,
                       const int* __restrict__ row_idx, const int* __restrict__ col_idx,
                       float* __restrict__ mask, float* __restrict__ partials)
{
    int idx = blockIdx.x*256 + threadIdx.x;
    unsigned ui = (unsigned)idx;
    int i = ui / S_;
    int j = (int)(ui - (unsigned)i*S_);
    float vr, lm;
    if (i == j) { vr = 0.f; lm = 1.f; }
    else {
        float t = lvr[(size_t)row_idx[idx]*VID_ + col_idx[idx]];
        float sg = 1.f/(1.f + expf(-t));
        vr = sg; lm = sg;
    }
    float dmat = (i >= j) ? exp2f((float)(i-j)*LOG2_GAMMAf) : 0.f;
    mask[idx] = dmat * lm;
    float s = vr;
    #pragma unroll
    for (int m=1; m<64; m<<=1) s += __shfl_xor(s, m, 64);
    __shared__ float ws4[4];
    if ((threadIdx.x & 63) == 0) ws4[threadIdx.x>>6] = s;
    __syncthreads();
    if (threadIdx.x == 0) partials[blockIdx.x] = ws4[0]+ws4[1]+ws4[2]+ws4[3];
}

__global__ __launch_bounds__(256) void k_loss(const float* __restrict__ partials,
                                              float* __restrict__ out_loss)
{
    float s = 0.f;
    for (int i = threadIdx.x; i < SS_/256; i += 256) s += partials[i];
    #pragma unroll
    for (int m=1; m<64; m<<=1) s += __shfl_xor(s, m, 64);
    __shared__ float ws4[4];
    if ((threadIdx.x & 63) == 0) ws4[threadIdx.x>>6] = s;
    __syncthreads();
    if (threadIdx.x == 0) out_loss[0] = (ws4[0]+ws4[1]+ws4[2]+ws4[3]) * (1.f/(float)SS_);
}

// ---------------- W_out transpose ----------------
__global__ __launch_bounds__(256) void k_wot(const float* __restrict__ Wout,
                                             float* __restrict__ WoT)
{
    int t = blockIdx.x*256 + threadIdx.x;
    WoT[t] = Wout[(t & 255)*DM_ + (t >> 8)];
}

// ---------------- QKV projection -> bf16 Q,K row-major + bf16 V^T ----------------
__global__ __launch_bounds__(256) void k_qkv(const float* __restrict__ src,
    const float* __restrict__ Wq, const float* __restrict__ Wk, const float* __restrict__ Wv,
    short* __restrict__ Qb, short* __restrict__ Kb, short* __restrict__ VT, int is_txt)
{
    __shared__ float xt[3][DM_][20];
    __shared__ __align__(16) short vt16[DM_][24];
    int tid = threadIdx.x;
    int r0 = blockIdx.x * 16;
    int b, srow0;
    if (is_txt) { b = r0 >> 5;  srow0 = r0 & 31; }
    else        { b = r0 >> 10; srow0 = TXT_ + (r0 & 1023); }

    for (int it = 0; it < 8; ++it) {
        int task = it*256 + tid;
        int k  = task >> 4;
        int rr = task & 15;
        int srow = srow0 + rr;
        float2 x01 = ((const float2*)(src + ((size_t)b*S_ + srow)*DM_))[k];
        if (is_txt) {
            float xe  = (float)(srow + 1) * (TWO_PIf/(32.f + 1e-6f));
            float arg = xe * exp2f(-((float)k*(1.f/128.f))*LOG2_10000f);
            float p0 = sinf(arg), p1 = cosf(arg);
            xt[0][2*k  ][rr] = x01.x + p0;
            xt[0][2*k+1][rr] = x01.y + p1;
            xt[1][2*k  ][rr] = x01.x + p0;
            xt[1][2*k+1][rr] = x01.y + p1;
        } else {
            int l = srow - TXT_;
            float inv_freq = exp2f(-((float)k*(1.f/128.f))*LOG2_10000f);
            float arg = (float)l * inv_freq;
            float sn = sinf(arg), cs = cosf(arg);
            float base = ((float)(2*k) + 102.4f) * (1.f/358.4f);
            float scale = exp2f(((float)l*(1.f/512.f)) * log2f(base));
            float rsc = 1.f/scale;
            float y0 = x01.x*cs - x01.y*sn;
            float y1 = x01.y*cs + x01.x*sn;
            xt[0][2*k  ][rr] = y0*scale;  xt[0][2*k+1][rr] = y1*scale;
            xt[1][2*k  ][rr] = y0*rsc;    xt[1][2*k+1][rr] = y1*rsc;
        }
        xt[2][2*k  ][rr] = x01.x;
        xt[2][2*k+1][rr] = x01.y;
    }
    __syncthreads();

    int og = tid & 63, rg = tid >> 6;
    float aq[4][4], ak[4][4], av[4][4];
    #pragma unroll
    for (int c=0;c<4;c++)
      #pragma unroll
      for (int jr=0;jr<4;jr++){ aq[c][jr]=0.f; ak[c][jr]=0.f; av[c][jr]=0.f; }

    for (int e = 0; e < DM_; ++e) {
        float4 xq = *(const float4*)&xt[0][e][rg*4];
        float4 xk = *(const float4*)&xt[1][e][rg*4];
        float4 xv = *(const float4*)&xt[2][e][rg*4];
        float4 wq = *(const float4*)&Wq[e*DM_ + og*4];
        float4 wk = *(const float4*)&Wk[e*DM_ + og*4];
        float4 wv = *(const float4*)&Wv[e*DM_ + og*4];
        float xqa[4] = {xq.x,xq.y,xq.z,xq.w};
        float xka[4] = {xk.x,xk.y,xk.z,xk.w};
        float xva[4] = {xv.x,xv.y,xv.z,xv.w};
        #pragma unroll
        for (int jr=0;jr<4;jr++){
            aq[0][jr] = fmaf(xqa[jr], wq.x, aq[0][jr]);
            aq[1][jr] = fmaf(xqa[jr], wq.y, aq[1][jr]);
            aq[2][jr] = fmaf(xqa[jr], wq.z, aq[2][jr]);
            aq[3][jr] = fmaf(xqa[jr], wq.w, aq[3][jr]);
            ak[0][jr] = fmaf(xka[jr], wk.x, ak[0][jr]);
            ak[1][jr] = fmaf(xka[jr], wk.y, ak[1][jr]);
            ak[2][jr] = fmaf(xka[jr], wk.z, ak[2][jr]);
            ak[3][jr] = fmaf(xka[jr], wk.w, ak[3][jr]);
            av[0][jr] = fmaf(xva[jr], wv.x, av[0][jr]);
            av[1][jr] = fmaf(xva[jr], wv.y, av[1][jr]);
            av[2][jr] = fmaf(xva[jr], wv.z, av[2][jr]);
            av[3][jr] = fmaf(xva[jr], wv.w, av[3][jr]);
        }
    }
    int head = og >> 3;
    int dbase = (og & 7) * 4;
    #pragma unroll
    for (int jr=0;jr<4;jr++){
        int srow = srow0 + rg*4 + jr;
        size_t off = ((size_t)(b*H_ + head)*S_ + srow)*DK_ + dbase;
        short4 q4; q4.x=f2bf(aq[0][jr]*RSQRT_DKf); q4.y=f2bf(aq[1][jr]*RSQRT_DKf);
                   q4.z=f2bf(aq[2][jr]*RSQRT_DKf); q4.w=f2bf(aq[3][jr]*RSQRT_DKf);
        short4 k4; k4.x=f2bf(ak[0][jr]); k4.y=f2bf(ak[1][jr]);
                   k4.z=f2bf(ak[2][jr]); k4.w=f2bf(ak[3][jr]);
        *(short4*)&Qb[off] = q4;
        *(short4*)&Kb[off] = k4;
        #pragma unroll
        for (int c=0;c<4;c++) vt16[og*4+c][rg*4+jr] = f2bf(av[c][jr]);
    }
    __syncthreads();
    {
        bf16x8 v0 = *(const bf16x8*)&vt16[tid][0];
        bf16x8 v1 = *(const bf16x8*)&vt16[tid][8];
        size_t vtoff = ((size_t)(b*H_ + (tid>>5))*DK_ + (tid&31))*SP_ + srow0;
        *(bf16x8*)&VT[vtoff]     = v0;
        *(bf16x8*)&VT[vtoff + 8] = v1;
    }
}

// ---------------- kernel A: denominators + ctx (NO att accumulator) ----------------
// P stride 1088 shorts = 544 dwords === 0 (mod 32): row term drops out of bank idx.
// XOR swizzle at 16B granularity: col' = col ^ ((lr&7)<<3)  -> write/read at bank floor.
__global__ __launch_bounds__(256, 4) void k_ctx(const short* __restrict__ Qb,
    const short* __restrict__ Kb, const short* __restrict__ VT,
    const float* __restrict__ mask, float* __restrict__ ctx, float* __restrict__ denomG)
{
    __shared__ __align__(16) short P[16][SP_];    // 34.0 KB
    __shared__ float rs[4][16];
    __shared__ float denom_l[16];
    __shared__ float pv_red[16][36];

    int tid  = threadIdx.x;
    int lane = tid & 63;
    int w    = tid >> 6;
    int b    = blockIdx.x & 15;   // qt-major: 16 adjacent blocks share mask rows
    int qt   = blockIdx.x >> 4;
    int q0   = qt * 16;

    int lr = lane & 15;
    int lg = lane >> 4;
    int dh = w & 1;
    int kh = w >> 1;
    int swq = (lr & 7) << 3;

    for (int h = 0; h < H_; ++h) {
        const short* Qp = Qb + ((size_t)(b*H_+h)*S_ + q0)*DK_;
        const short* Kp = Kb + (size_t)(b*H_+h)*S_*DK_;
        bf16x8 qfrag = *(const bf16x8*)(Qp + lr*DK_ + lg*8);

        // ---- phase 1: scores + exp -> P ----
        float rssum = 0.f;
        #pragma unroll
        for (int t = 0; t < 17; ++t) {
            int k0 = t*64 + w*16;
            int colbase = k0 + lg*4;
            short4 s4;
            if (k0 < S_) {
                bf16x8 kf = *(const bf16x8*)(Kp + (size_t)(k0+lr)*DK_ + lg*8);
                f32x4 acc = {0.f,0.f,0.f,0.f};
                acc = __builtin_amdgcn_mfma_f32_16x16x32_bf16(kf, qfrag, acc, 0, 0, 0);
                float4 m4 = *(const float4*)(mask + (size_t)(q0+lr)*S_ + colbase);
                float e0 = __expf(acc[0]*m4.x);
                float e1 = __expf(acc[1]*m4.y);
                float e2 = __expf(acc[2]*m4.z);
                float e3 = __expf(acc[3]*m4.w);
                rssum += (e0+e1) + (e2+e3);
                s4.x=f2bf(e0); s4.y=f2bf(e1); s4.z=f2bf(e2); s4.w=f2bf(e3);
            } else {
                s4.x=0; s4.y=0; s4.z=0; s4.w=0;
            }
            *(short4*)&P[lr][colbase ^ swq] = s4;
        }
        // ---- denominators ----
        rssum += __shfl_xor(rssum, 16, 64);
        rssum += __shfl_xor(rssum, 32, 64);
        if (lane < 16) rs[w][lr] = rssum;
        __syncthreads();
        if (tid < 16) {
            float rd = 1.f/(rs[0][tid]+rs[1][tid]+rs[2][tid]+rs[3][tid]);
            denom_l[tid] = rd;
            denomG[(size_t)(b*H_+h)*S_ + q0 + tid] = rd;
        }
        __syncthreads();

        // ---- PV ----
        const short* Vp = VT + ((size_t)(b*H_+h)*DK_ + dh*16 + lr)*SP_;
        f32x4 pvacc = {0.f,0.f,0.f,0.f};
        #pragma unroll
        for (int t2 = 0; t2 < 17; ++t2) {
            int kb = (kh*17 + t2)*32;
            bf16x8 pf = *(const bf16x8*)&P[lr][(kb + lg*8) ^ swq];
            bf16x8 vf = *(const bf16x8*)(Vp + kb + lg*8);
            pvacc = __builtin_amdgcn_mfma_f32_16x16x32_bf16(pf, vf, pvacc, 0, 0, 0);
        }
        if (kh == 1) {
            #pragma unroll
            for (int r = 0; r < 4; ++r) pv_red[lg*4+r][dh*16+lr] = pvacc[r];
        }
        __syncthreads();
        if (kh == 0) {
            #pragma unroll
            for (int r = 0; r < 4; ++r) {
                int qq = lg*4 + r;
                float v = pvacc[r] + pv_red[qq][dh*16+lr];
                ctx[((size_t)b*S_ + q0+qq)*DM_ + h*DK_ + dh*16 + lr] = v * denom_l[qq];
            }
        }
        __syncthreads();
    }
}

// ---------------- kernel B: att by score recompute, t-outer / h-inner ----------------
// mfma(A=Q, B=K): D rows = q (4*lg+reg), col = k (lane&15). One f32x4 live accumulator.
__global__ __launch_bounds__(256, 6) void k_att(const short* __restrict__ Qb,
    const short* __restrict__ Kb, const float* __restrict__ mask,
    const float* __restrict__ denomG, float* __restrict__ att)
{
    __shared__ float rd_l[8][16];
    int tid  = threadIdx.x;
    int lane = tid & 63;
    int w    = tid >> 6;
    int b    = blockIdx.x & 15;
    int qt   = blockIdx.x >> 4;
    int q0   = qt * 16;

    if (tid < 128)
        rd_l[tid>>4][tid&15] = denomG[(size_t)(b*H_+(tid>>4))*S_ + q0 + (tid&15)] * 0.125f;
    __syncthreads();

    int lr = lane & 15;
    int lg = lane >> 4;

    for (int t = 0; t < 17; ++t) {
        int k0 = t*64 + w*16;
        if (k0 >= S_) continue;          // only t=16, w>=2
        float mk0 = mask[(size_t)(q0+4*lg+0)*S_ + k0+lr];
        float mk1 = mask[(size_t)(q0+4*lg+1)*S_ + k0+lr];
        float mk2 = mask[(size_t)(q0+4*lg+2)*S_ + k0+lr];
        float mk3 = mask[(size_t)(q0+4*lg+3)*S_ + k0+lr];
        f32x4 a = {0.f,0.f,0.f,0.f};
        for (int h = 0; h < H_; ++h) {
            bf16x8 qfrag = *(const bf16x8*)(Qb + ((size_t)(b*H_+h)*S_ + q0+lr)*DK_ + lg*8);
            bf16x8 kfrag = *(const bf16x8*)(Kb + ((size_t)(b*H_+h)*S_ + k0+lr)*DK_ + lg*8);
            f32x4 s = {0.f,0.f,0.f,0.f};
            s = __builtin_amdgcn_mfma_f32_16x16x32_bf16(qfrag, kfrag, s, 0, 0, 0);
            a[0] = fmaf(__expf(s[0]*mk0), rd_l[h][4*lg+0], a[0]);
            a[1] = fmaf(__expf(s[1]*mk1), rd_l[h][4*lg+1], a[1]);
            a[2] = fmaf(__expf(s[2]*mk2), rd_l[h][4*lg+2], a[2]);
            a[3] = fmaf(__expf(s[3]*mk3), rd_l[h][4*lg+3], a[3]);
        }
        att[((size_t)b*S_ + q0+4*lg+0)*S_ + k0+lr] = a[0];
        att[((size_t)b*S_ + q0+4*lg+1)*S_ + k0+lr] = a[1];
        att[((size_t)b*S_ + q0+4*lg+2)*S_ + k0+lr] = a[2];
        att[((size_t)b*S_ + q0+4*lg+3)*S_ + k0+lr] = a[3];
    }
}

// ---------------- out projection ----------------
__global__ __launch_bounds__(256) void k_outproj(const float* __restrict__ ctxp,
    const float* __restrict__ WoT, const float* __restrict__ bias, float* __restrict__ out)
{
    __shared__ float ct[DM_][20];
    int tid = threadIdx.x;
    int r0 = blockIdx.x * 16;
    for (int it = 0; it < 16; ++it) {
        int task = it*256 + tid;
        int col = task >> 4;
        int rr  = task & 15;
        ct[col][rr] = ctxp[(size_t)(r0+rr)*DM_ + col];
    }
    __syncthreads();
    int og = tid & 63, rg = tid >> 6;
    float acc[4][4];
    #pragma unroll
    for (int c=0;c<4;c++)
      #pragma unroll
      for (int jr=0;jr<4;jr++) acc[c][jr] = 0.f;
    for (int e = 0; e < DM_; ++e){
        float4 x4 = *(const float4*)&ct[e][rg*4];
        float4 w4 = *(const float4*)&WoT[e*DM_ + og*4];
        float xa[4] = {x4.x,x4.y,x4.z,x4.w};
        #pragma unroll
        for (int jr=0;jr<4;jr++){
            acc[0][jr] = fmaf(xa[jr], w4.x, acc[0][jr]);
            acc[1][jr] = fmaf(xa[jr], w4.y, acc[1][jr]);
            acc[2][jr] = fmaf(xa[jr], w4.z, acc[2][jr]);
            acc[3][jr] = fmaf(xa[jr], w4.w, acc[3][jr]);
        }
    }
    float4 b4 = *(const float4*)&bias[og*4];
    #pragma unroll
    for (int jr=0;jr<4;jr++){
        int r = r0 + rg*4 + jr;
        float4 o4 = make_float4(acc[0][jr]+b4.x, acc[1][jr]+b4.y,
                                acc[2][jr]+b4.z, acc[3][jr]+b4.w);
        *(float4*)&out[(size_t)r*DM_ + og*4] = o4;
    }
}

extern "C" void kernel_launch(void* const* d_in, const int* in_sizes, int n_in,
                              void* d_out, int out_size, void* d_ws, size_t ws_size,
                              hipStream_t stream)
{
    (void)in_sizes; (void)n_in; (void)out_size; (void)ws_size;
    const float* src  = (const float*)d_in[0];
    const float* Wtq  = (const float*)d_in[1];
    const float* Wtk  = (const float*)d_in[2];
    const float* Wtv  = (const float*)d_in[3];
    const float* Wvq  = (const float*)d_in[4];
    const float* Wvk  = (const float*)d_in[5];
    const float* Wvv  = (const float*)d_in[6];
    const float* lvr  = (const float*)d_in[7];
    const float* Wout = (const float*)d_in[8];
    const float* bout = (const float*)d_in[9];
    const int*   rid  = (const int*)d_in[10];
    const int*   cid  = (const int*)d_in[11];

    const size_t QKV_SH = (size_t)B_*H_*S_*DK_;    // shorts per Q/K buffer
    float* ws       = (float*)d_ws;
    float* mask     = ws;                           // SS_
    float* ctx      = mask + SS_;                   // B*S*DM
    float* WoT      = ctx + (size_t)B_*S_*DM_;      // 65536
    float* partials = WoT + DM_*DM_;                // 4356
    float* denomG   = partials + 4356;              // B*H*S = 135168
    short* Qb       = (short*)(denomG + (size_t)B_*H_*S_);
    short* Kb       = Qb + QKV_SH;
    short* VT       = Kb + QKV_SH;

    float* out  = (float*)d_out;
    float* att  = out + (size_t)B_*S_*DM_;
    float* loss = att + (size_t)B_*S_*S_;

    k_mask<<<SS_/256, 256, 0, stream>>>(lvr, rid, cid, mask, partials);
    k_wot<<<DM_*DM_/256, 256, 0, stream>>>(Wout, WoT);
    k_qkv<<<(B_*TXT_)/16, 256, 0, stream>>>(src, Wtq, Wtk, Wtv, Qb, Kb, VT, 1);
    k_qkv<<<(B_*VID_)/16, 256, 0, stream>>>(src, Wvq, Wvk, Wvv, Qb, Kb, VT, 0);
    k_ctx<<<B_*NQT_, 256, 0, stream>>>(Qb, Kb, VT, mask, ctx, denomG);
    k_att<<<B_*NQT_, 256, 0, stream>>>(Qb, Kb, mask, denomG, att);
    k_outproj<<<(B_*S_)/16, 256, 0, stream>>>(ctx, WoT, bout, out);
    k_loss<<<1, 256, 0, stream>>>(partials, loss);
}